// Round 3
// baseline (164.270 us; speedup 1.0000x reference)
//
#include <hip/hip_runtime.h>
#include <cstddef>
#include <cstdint>

// ATTRIBUTION ROUND #2: kernels byte-identical to the round-0 baseline.
// pool_kernel launched 4x (idempotent: reads SAT, rewrites same output) so
//   dur_total ~= baseline(114.5us) + 3 * dur(pool)
// Round-2 result already established: rowscan ~= 11.9us (at its traffic floor).
// This round splits the remaining ~102us between colscan and pool.

// Channel-interleaved, LINE-ALIGNED SAT: sat[(y*1026 + x)*8 + c], y,x in
// [0,1025), c in [0,8). Row stride = 1026*8 f32 = 8208 f32 = 32832 B = 513
// full 64B lines.
#define SATW_PAD 1026
#define W8   8200          // used floats per y-row (1025 * 8)
#define W8P  8208          // padded floats per y-row (1026 * 8)
#define NCH  8
#define STRIP 16           // f32 columns per colscan block = exactly one 64B line/row
#define NSTRIP (W8P / STRIP)   // 513, exact

// ---------------- Kernel A: row prefix sums, planar in -> interleaved out ----
__global__ __launch_bounds__(256) void rowscan_kernel(const float* __restrict__ in,
                                                      float* __restrict__ sat) {
    const int y    = blockIdx.x;
    const int t    = threadIdx.x;
    const int lane = t & 63;
    const int wv   = t >> 6;

    __shared__ float lds[NCH][1024];

    for (int k = 0; k < 2; ++k) {
        const int c = wv * 2 + k;
        const float4* r4 = (const float4*)(in + ((size_t)c * 1024 + y) * 1024);
        double chunkbase = 0.0;
#pragma unroll
        for (int j = 0; j < 4; ++j) {           // 4 chunks of 256 floats
            float4 a = r4[lane + 64 * j];       // coalesced per instruction
            double v0 = a.x, v1 = a.y, v2 = a.z, v3 = a.w;
            double s = v0 + v1 + v2 + v3;
            double ps = s;                      // inclusive scan of lane sums
#pragma unroll
            for (int off = 1; off < 64; off <<= 1) {
                double n = __shfl_up(ps, off, 64);
                if (lane >= off) ps += n;
            }
            double base = chunkbase + ps - s;   // exclusive prefix for this lane
            double p0 = base + v0, p1 = p0 + v1, p2 = p1 + v2, p3 = p2 + v3;
            ((float4*)lds[c])[lane + 64 * j] =
                make_float4((float)p0, (float)p1, (float)p2, (float)p3);
            chunkbase += __shfl(ps, 63, 64);    // chunk total broadcast
        }
    }
    __syncthreads();

    // Interleaved row write: flat f -> x = f>>3, c = f&7;
    // val = (1<=x<=1024) ? prefix[x-1] : 0 (x==0 boundary, x==1025 pad)
    float* orow = sat + (size_t)(y + 1) * W8P;
    for (int f4 = t; f4 < W8P / 4; f4 += 256) {
        int f = f4 * 4;
        float4 o;
        float* po = (float*)&o;
#pragma unroll
        for (int j = 0; j < 4; ++j) {
            int ff = f + j;
            int x = ff >> 3, c = ff & 7;
            po[j] = (x >= 1 && x <= 1024) ? lds[c][x - 1] : 0.0f;
        }
        ((float4*)orow)[f4] = o;                // 64B-line-aligned store
    }
}

// ---------------- Kernel B: register-resident column scan (round-0 version) --
__global__ __launch_bounds__(256) void colscan_block(float* __restrict__ sat) {
    const int t    = threadIdx.x;
    const int lane = t & 63;
    const int w    = t >> 6;         // wave 0..3
    const int rg   = lane >> 2;      // row sub-chunk 0..15
    const int q    = lane & 3;       // float4 slot 0..3
    const int c0   = blockIdx.x * STRIP + q * 4;   // always < W8P, 16B-aligned

    float* p0 = sat + (size_t)(1 + w * 256 + rg * 16) * W8P + c0;

    float4 v[16];
#pragma unroll
    for (int k = 0; k < 16; ++k)
        v[k] = *(const float4*)(p0 + (size_t)k * W8P);

    // per-lane f64 totals over its 16 contiguous rows
    double T0 = 0, T1 = 0, T2 = 0, T3 = 0;
#pragma unroll
    for (int k = 0; k < 16; ++k) {
        T0 += v[k].x; T1 += v[k].y; T2 += v[k].z; T3 += v[k].w;
    }

    // in-wave inclusive scan over rg (lanes with same q are 4 apart)
    double i0 = T0, i1 = T1, i2 = T2, i3 = T3;
#pragma unroll
    for (int s = 4; s <= 32; s <<= 1) {
        double a0 = __shfl_up(i0, s, 64), a1 = __shfl_up(i1, s, 64);
        double a2 = __shfl_up(i2, s, 64), a3 = __shfl_up(i3, s, 64);
        if (lane >= s) { i0 += a0; i1 += a1; i2 += a2; i3 += a3; }
    }
    double e0 = i0 - T0, e1 = i1 - T1, e2 = i2 - T2, e3 = i3 - T3;

    __shared__ double wt[4][4][4];   // [wave][q][comp] wave totals
    if (lane >= 60) {                // rg==15 lane holds the wave-inclusive total
        wt[w][q][0] = i0; wt[w][q][1] = i1; wt[w][q][2] = i2; wt[w][q][3] = i3;
    }
    __syncthreads();
    double b0 = e0, b1 = e1, b2 = e2, b3 = e3;
    for (int w2 = 0; w2 < w; ++w2) {
        b0 += wt[w2][q][0]; b1 += wt[w2][q][1];
        b2 += wt[w2][q][2]; b3 += wt[w2][q][3];
    }

#pragma unroll
    for (int k = 0; k < 16; ++k) {
        b0 += v[k].x; b1 += v[k].y; b2 += v[k].z; b3 += v[k].w;
        *(float4*)(p0 + (size_t)k * W8P) =
            make_float4((float)b0, (float)b1, (float)b2, (float)b3);
    }

    // SAT row y=0 is zeros for this strip
    if (t < 4) {
        int cz = blockIdx.x * STRIP + t * 4;
        *(float4*)(sat + cz) = make_float4(0.f, 0.f, 0.f, 0.f);
    }
}

// ---------------- Kernel C: one wave per ROI, all 8 channels (f32 math) ------
__global__ __launch_bounds__(256) void pool_kernel(const float* __restrict__ sat,
                                                   const int* __restrict__ rois,
                                                   float* __restrict__ out,
                                                   int n_roi) {
    int lane = threadIdx.x & 63;
    int roi  = (blockIdx.x * blockDim.x + threadIdx.x) >> 6;
    if (roi >= n_roi) return;

    const int4 rv = ((const int4*)rois)[roi];   // [y0, x0, y1, x1] pixel coords
    int ymin = rv.x >> 5;                       // / FEAT_STRIDE(32)
    int xmin = rv.y >> 5;
    int Ly   = (rv.z >> 5) + 1 - ymin;
    int Lx   = (rv.w >> 5) + 1 - xmin;

    float acc[NCH];
#pragma unroll
    for (int c = 0; c < NCH; ++c) acc[c] = 0.0f;

    if (lane < 49) {
        int by = lane / 7;
        int bx = lane - by * 7;
        int ylo = ymin + (by * Ly) / 7;
        int yhi = ymin + ((by + 1) * Ly + 6) / 7;
        int xlo = xmin + (bx * Lx) / 7;
        int xhi = xmin + ((bx + 1) * Lx + 6) / 7;
        float inv = 1.0f / (float)((yhi - ylo) * (xhi - xlo));

        float4 a[2], b[2], c4[2], d[2];
        const float4* hh = (const float4*)(sat + ((size_t)yhi * SATW_PAD + xhi) * NCH);
        const float4* lh = (const float4*)(sat + ((size_t)ylo * SATW_PAD + xhi) * NCH);
        const float4* hl = (const float4*)(sat + ((size_t)yhi * SATW_PAD + xlo) * NCH);
        const float4* ll = (const float4*)(sat + ((size_t)ylo * SATW_PAD + xlo) * NCH);
        a[0] = hh[0]; a[1] = hh[1];
        b[0] = lh[0]; b[1] = lh[1];
        c4[0] = hl[0]; c4[1] = hl[1];
        d[0] = ll[0]; d[1] = ll[1];
        const float* fa = (const float*)a;
        const float* fb = (const float*)b;
        const float* fc = (const float*)c4;
        const float* fd = (const float*)d;
#pragma unroll
        for (int c = 0; c < NCH; ++c)
            acc[c] = (fa[c] - fb[c] - fc[c] + fd[c]) * inv;
    }

#pragma unroll
    for (int off = 32; off; off >>= 1) {
#pragma unroll
        for (int c = 0; c < NCH; ++c) acc[c] += __shfl_down(acc[c], off, 64);
    }

    if (lane == 0) {
        const float k = 1.0f / 49.0f;
        float4* po = (float4*)(out + (size_t)roi * NCH);
        po[0] = make_float4(acc[0] * k, acc[1] * k, acc[2] * k, acc[3] * k);
        po[1] = make_float4(acc[4] * k, acc[5] * k, acc[6] * k, acc[7] * k);
    }
}

extern "C" void kernel_launch(void* const* d_in, const int* in_sizes, int n_in,
                              void* d_out, int out_size, void* d_ws, size_t ws_size,
                              hipStream_t stream) {
    const float* conv = (const float*)d_in[0];   // (1, 8, 1024, 1024) f32
    const int*   rois = (const int*)d_in[1];     // (8192, 4) int32
    float*       out  = (float*)d_out;           // (8192, 2, 4) f32 flat
    int n_roi = in_sizes[1] / 4;

    float* sat = (float*)d_ws;                   // 1025 * 8208 * 4 = 33.65 MB

    rowscan_kernel<<<1024, 256, 0, stream>>>(conv, sat);
    colscan_block<<<NSTRIP, 256, 0, stream>>>(sat);
    // ---- attribution: pool x4 (idempotent); dur ~= base + 3*C ----
    pool_kernel<<<(n_roi + 3) / 4, 256, 0, stream>>>(sat, rois, out, n_roi);
    pool_kernel<<<(n_roi + 3) / 4, 256, 0, stream>>>(sat, rois, out, n_roi);
    pool_kernel<<<(n_roi + 3) / 4, 256, 0, stream>>>(sat, rois, out, n_roi);
    pool_kernel<<<(n_roi + 3) / 4, 256, 0, stream>>>(sat, rois, out, n_roi);
}

// Round 5
// 117.005 us; speedup vs baseline: 1.4040x; 1.4040x over previous
//
#include <hip/hip_runtime.h>
#include <cstddef>
#include <cstdint>

// SAT layout unchanged: channel-interleaved, line-aligned:
// sat[(y*1026 + x)*8 + c], row stride 1026*8 f32 = 32832 B = 513 64B lines.
//
// ROUND 5 (resubmit of round 4 — container-level infra failure, no verdict):
// colscan replaced by a 3-kernel band decomposition where EVERY global
// load/store instruction is 1KB-contiguous per wave (old colscan's
// instructions each touched 16 scattered 64B lines at 32KB stride; measured
// ~0.8 TB/s effective = ~85us of the 114.5us baseline).
//   B1 band_sum:    per-band (16-row) f64 column sums      (33.6 MB R, 4.2 MB W)
//   B2 band_prefix: exclusive prefix over 64 bands/column  (4.2 MB R/W)
//   B3 band_apply:  reload rows, add prefix, store SAT     (37.8 MB R, 33.6 MB W)
// Per-lane MLP identical to old colscan (16 strided loads in flight), so this
// round is also the controlled test of the per-instruction-contiguity theory.

#define SATW_PAD 1026
#define W8   8200          // used floats per y-row (1025 * 8); cols >= 8200 are pad
#define W8P  8208          // padded floats per y-row (1026 * 8)
#define NCH  8

#define NBAND 64           // bands over the 1024 data rows
#define BROWS 16           // rows per band
#define CHUNK_F32 1024     // f32 columns per block (4 KB)
#define NCHUNK 9           // 8 full chunks + tail (cols 8192..8199)

// ---------------- Kernel A: row prefix sums (unchanged, at traffic floor) ----
__global__ __launch_bounds__(256) void rowscan_kernel(const float* __restrict__ in,
                                                      float* __restrict__ sat) {
    const int y    = blockIdx.x;
    const int t    = threadIdx.x;
    const int lane = t & 63;
    const int wv   = t >> 6;

    __shared__ float lds[NCH][1024];

    for (int k = 0; k < 2; ++k) {
        const int c = wv * 2 + k;
        const float4* r4 = (const float4*)(in + ((size_t)c * 1024 + y) * 1024);
        double chunkbase = 0.0;
#pragma unroll
        for (int j = 0; j < 4; ++j) {           // 4 chunks of 256 floats
            float4 a = r4[lane + 64 * j];       // coalesced per instruction
            double v0 = a.x, v1 = a.y, v2 = a.z, v3 = a.w;
            double s = v0 + v1 + v2 + v3;
            double ps = s;                      // inclusive scan of lane sums
#pragma unroll
            for (int off = 1; off < 64; off <<= 1) {
                double n = __shfl_up(ps, off, 64);
                if (lane >= off) ps += n;
            }
            double base = chunkbase + ps - s;   // exclusive prefix for this lane
            double p0 = base + v0, p1 = p0 + v1, p2 = p1 + v2, p3 = p2 + v3;
            ((float4*)lds[c])[lane + 64 * j] =
                make_float4((float)p0, (float)p1, (float)p2, (float)p3);
            chunkbase += __shfl(ps, 63, 64);    // chunk total broadcast
        }
    }
    __syncthreads();

    float* orow = sat + (size_t)(y + 1) * W8P;
    for (int f4 = t; f4 < W8P / 4; f4 += 256) {
        int f = f4 * 4;
        float4 o;
        float* po = (float*)&o;
#pragma unroll
        for (int j = 0; j < 4; ++j) {
            int ff = f + j;
            int x = ff >> 3, c = ff & 7;
            po[j] = (x >= 1 && x <= 1024) ? lds[c][x - 1] : 0.0f;
        }
        ((float4*)orow)[f4] = o;                // 64B-line-aligned store
    }
}

// ---------------- B1: band column sums (every instruction contiguous) --------
// Block (chunk c, band b): thread t owns f32 cols [c*1024+4t, +4) for the
// band's 16 rows. Wave load instruction k = 64 lanes x float4 = 1 KB
// contiguous from row (1+16b+k). No LDS, no cross-lane ops.
__global__ __launch_bounds__(256) void band_sum(const float* __restrict__ sat,
                                                double* __restrict__ bsum) {
    const int c = blockIdx.x;
    const int b = blockIdx.y;
    const int t = threadIdx.x;
    const int col0 = c * CHUNK_F32 + t * 4;
    if (col0 >= W8) return;                     // tail chunk: only cols < 8200

    const float* p = sat + (size_t)(1 + b * BROWS) * W8P + col0;
    float4 v[BROWS];
#pragma unroll
    for (int k = 0; k < BROWS; ++k)
        v[k] = *(const float4*)(p + (size_t)k * W8P);

    double s0 = 0, s1 = 0, s2 = 0, s3 = 0;
#pragma unroll
    for (int k = 0; k < BROWS; ++k) {
        s0 += v[k].x; s1 += v[k].y; s2 += v[k].z; s3 += v[k].w;
    }

    double* o = bsum + (size_t)b * W8P + col0;  // 2 KB contiguous per wave
    double2 lo, hi;
    lo.x = s0; lo.y = s1; hi.x = s2; hi.y = s3;
    *(double2*)o       = lo;
    *((double2*)o + 1) = hi;
}

// ---------------- B2: exclusive prefix over 64 bands per column --------------
// One wave per 64B line-column (16 f32 cols = 8 double2 slots). Lane
// (rg=lane>>3, s=lane&7): rg owns bands [8rg, 8rg+8) serially at slot s;
// 3-step shuffle scan combines the 8 band-groups. Only 8.4 MB total.
__global__ __launch_bounds__(64) void band_prefix(double* __restrict__ bsum) {
    const int lane = threadIdx.x;
    const int rg   = lane >> 3;       // band group 0..7
    const int s    = lane & 7;        // double2 slot 0..7
    const size_t base = (size_t)blockIdx.x * 16 + (size_t)s * 2;

    double2 v[8];
#pragma unroll
    for (int k = 0; k < 8; ++k)
        v[k] = *(const double2*)(bsum + (size_t)(rg * 8 + k) * W8P + base);

    double i0 = 0, i1 = 0;
    double incl0[8], incl1[8];
#pragma unroll
    for (int k = 0; k < 8; ++k) {
        i0 += v[k].x; i1 += v[k].y;
        incl0[k] = i0; incl1[k] = i1;
    }

    // scan group totals across rg (lane stride 8): lane>=off <=> rg>=off/8
    double a0 = i0, a1 = i1;
#pragma unroll
    for (int off = 8; off <= 32; off <<= 1) {
        double u0 = __shfl_up(a0, off, 64);
        double u1 = __shfl_up(a1, off, 64);
        if (lane >= off) { a0 += u0; a1 += u1; }
    }
    const double base0 = a0 - i0, base1 = a1 - i1;   // exclusive over groups

#pragma unroll
    for (int k = 0; k < 8; ++k) {
        double2 e;
        e.x = base0 + incl0[k] - v[k].x;
        e.y = base1 + incl1[k] - v[k].y;
        *(double2*)(bsum + (size_t)(rg * 8 + k) * W8P + base) = e;
    }
}

// ---------------- B3: apply band prefix, produce final SAT -------------------
// Same geometry as B1. Loads 16 rows (contiguous instructions), adds the f64
// exclusive band prefix, stores the running f64 prefix rounded to f32.
// Band 0 blocks also zero SAT row 0.
__global__ __launch_bounds__(256) void band_apply(float* __restrict__ sat,
                                                  const double* __restrict__ bpre) {
    const int c = blockIdx.x;
    const int b = blockIdx.y;
    const int t = threadIdx.x;
    const int col0 = c * CHUNK_F32 + t * 4;
    if (col0 >= W8) return;

    const double* q = bpre + (size_t)b * W8P + col0;
    double2 qlo = *(const double2*)q;
    double2 qhi = *((const double2*)q + 1);
    double a0 = qlo.x, a1 = qlo.y, a2 = qhi.x, a3 = qhi.y;

    float* p = sat + (size_t)(1 + b * BROWS) * W8P + col0;
    float4 v[BROWS];
#pragma unroll
    for (int k = 0; k < BROWS; ++k)
        v[k] = *(const float4*)(p + (size_t)k * W8P);

#pragma unroll
    for (int k = 0; k < BROWS; ++k) {
        a0 += v[k].x; a1 += v[k].y; a2 += v[k].z; a3 += v[k].w;
        *(float4*)(p + (size_t)k * W8P) =
            make_float4((float)a0, (float)a1, (float)a2, (float)a3);
    }

    if (b == 0)                                  // SAT row y=0 is zeros
        *(float4*)(sat + col0) = make_float4(0.f, 0.f, 0.f, 0.f);
}

// ---------------- Kernel C: one wave per ROI (unchanged) ---------------------
__global__ __launch_bounds__(256) void pool_kernel(const float* __restrict__ sat,
                                                   const int* __restrict__ rois,
                                                   float* __restrict__ out,
                                                   int n_roi) {
    int lane = threadIdx.x & 63;
    int roi  = (blockIdx.x * blockDim.x + threadIdx.x) >> 6;
    if (roi >= n_roi) return;

    const int4 rv = ((const int4*)rois)[roi];   // [y0, x0, y1, x1] pixel coords
    int ymin = rv.x >> 5;                       // / FEAT_STRIDE(32)
    int xmin = rv.y >> 5;
    int Ly   = (rv.z >> 5) + 1 - ymin;
    int Lx   = (rv.w >> 5) + 1 - xmin;

    float acc[NCH];
#pragma unroll
    for (int c = 0; c < NCH; ++c) acc[c] = 0.0f;

    if (lane < 49) {
        int by = lane / 7;
        int bx = lane - by * 7;
        int ylo = ymin + (by * Ly) / 7;
        int yhi = ymin + ((by + 1) * Ly + 6) / 7;
        int xlo = xmin + (bx * Lx) / 7;
        int xhi = xmin + ((bx + 1) * Lx + 6) / 7;
        float inv = 1.0f / (float)((yhi - ylo) * (xhi - xlo));

        float4 a[2], b[2], c4[2], d[2];
        const float4* hh = (const float4*)(sat + ((size_t)yhi * SATW_PAD + xhi) * NCH);
        const float4* lh = (const float4*)(sat + ((size_t)ylo * SATW_PAD + xhi) * NCH);
        const float4* hl = (const float4*)(sat + ((size_t)yhi * SATW_PAD + xlo) * NCH);
        const float4* ll = (const float4*)(sat + ((size_t)ylo * SATW_PAD + xlo) * NCH);
        a[0] = hh[0]; a[1] = hh[1];
        b[0] = lh[0]; b[1] = lh[1];
        c4[0] = hl[0]; c4[1] = hl[1];
        d[0] = ll[0]; d[1] = ll[1];
        const float* fa = (const float*)a;
        const float* fb = (const float*)b;
        const float* fc = (const float*)c4;
        const float* fd = (const float*)d;
#pragma unroll
        for (int c = 0; c < NCH; ++c)
            acc[c] = (fa[c] - fb[c] - fc[c] + fd[c]) * inv;
    }

#pragma unroll
    for (int off = 32; off; off >>= 1) {
#pragma unroll
        for (int c = 0; c < NCH; ++c) acc[c] += __shfl_down(acc[c], off, 64);
    }

    if (lane == 0) {
        const float k = 1.0f / 49.0f;
        float4* po = (float4*)(out + (size_t)roi * NCH);
        po[0] = make_float4(acc[0] * k, acc[1] * k, acc[2] * k, acc[3] * k);
        po[1] = make_float4(acc[4] * k, acc[5] * k, acc[6] * k, acc[7] * k);
    }
}

extern "C" void kernel_launch(void* const* d_in, const int* in_sizes, int n_in,
                              void* d_out, int out_size, void* d_ws, size_t ws_size,
                              hipStream_t stream) {
    const float* conv = (const float*)d_in[0];   // (1, 8, 1024, 1024) f32
    const int*   rois = (const int*)d_in[1];     // (8192, 4) int32
    float*       out  = (float*)d_out;           // (8192, 2, 4) f32 flat
    int n_roi = in_sizes[1] / 4;

    float*  sat  = (float*)d_ws;                          // 33.65 MB
    double* bsum = (double*)((char*)d_ws + 33652992);     // 64*8208*8 = 4.2 MB

    rowscan_kernel<<<1024, 256, 0, stream>>>(conv, sat);
    band_sum   <<<dim3(NCHUNK, NBAND), 256, 0, stream>>>(sat, bsum);
    band_prefix<<<513, 64, 0, stream>>>(bsum);
    band_apply <<<dim3(NCHUNK, NBAND), 256, 0, stream>>>(sat, bsum);
    pool_kernel<<<(n_roi + 3) / 4, 256, 0, stream>>>(sat, rois, out, n_roi);
}